// Round 4
// baseline (424.483 us; speedup 1.0000x reference)
//
#include <hip/hip_runtime.h>
#include <math.h>

typedef __bf16 bf16x8 __attribute__((ext_vector_type(8)));
typedef __bf16 bf16x4 __attribute__((ext_vector_type(4)));
typedef float  f32x4  __attribute__((ext_vector_type(4)));
typedef unsigned int u32x4 __attribute__((ext_vector_type(4)));

#define B_   2
#define N_   4096
#define D_   512
#define H_   8
#define FF_  2048
#define BN_  (B_*N_)
static constexpr float SCALE_ = 0.04419417382415922f;  // 512^-0.5
static constexpr float LOG2E_ = 1.44269504088896341f;
static constexpr float SCALE_L2E_ = SCALE_ * LOG2E_;   // fold log2e into Q scale

#define GLOAD_LDS16(g, l) __builtin_amdgcn_global_load_lds( \
    (const __attribute__((address_space(1))) void*)(g),     \
    (__attribute__((address_space(3))) void*)(l), 16, 0, 0)

// ---------------- weight transpose f32[R][C] -> bf16[C][R] ----------------
__global__ void transpose_to_bf16(const float* __restrict__ in, __bf16* __restrict__ out,
                                  int R, int C) {
    __shared__ float tile[32][33];
    const int c0 = blockIdx.x * 32, r0 = blockIdx.y * 32;
    const int tx = threadIdx.x, ty = threadIdx.y;   // (32,8)
#pragma unroll
    for (int i = 0; i < 4; ++i)
        tile[ty + 8*i][tx] = in[(size_t)(r0 + ty + 8*i) * C + c0 + tx];
    __syncthreads();
#pragma unroll
    for (int i = 0; i < 4; ++i)
        out[(size_t)(c0 + ty + 8*i) * R + r0 + tx] = (__bf16)tile[tx][ty + 8*i];
}

// ---------------- f32 -> bf16 elementwise (dist), folds log2e ----------------
__global__ void cvt_bf16(const float* __restrict__ in, __bf16* __restrict__ out, int n4) {
    int i = blockIdx.x * blockDim.x + threadIdx.x;
    const int stride = gridDim.x * blockDim.x;
    for (; i < n4; i += stride) {
        float4 v = ((const float4*)in)[i];
        bf16x4 o;
        o[0] = (__bf16)(v.x * LOG2E_); o[1] = (__bf16)(v.y * LOG2E_);
        o[2] = (__bf16)(v.z * LOG2E_); o[3] = (__bf16)(v.w * LOG2E_);
        ((bf16x4*)out)[i] = o;
    }
}

// ---------------- LayerNorm f32 -> bf16, one row (512) per block of 128 ----------------
__global__ __launch_bounds__(128)
void ln_kernel(const float* __restrict__ x, const float* __restrict__ w,
               const float* __restrict__ b, __bf16* __restrict__ out) {
    const int row = blockIdx.x, t = threadIdx.x;
    const float4 v = *(const float4*)&x[(size_t)row * 512 + t * 4];
    float s  = v.x + v.y + v.z + v.w;
    float sq = v.x*v.x + v.y*v.y + v.z*v.z + v.w*v.w;
#pragma unroll
    for (int mk = 1; mk < 64; mk <<= 1) { s += __shfl_xor(s, mk); sq += __shfl_xor(sq, mk); }
    __shared__ float ps[2][2];
    if ((t & 63) == 0) { ps[t >> 6][0] = s; ps[t >> 6][1] = sq; }
    __syncthreads();
    s = ps[0][0] + ps[1][0]; sq = ps[0][1] + ps[1][1];
    const float mu  = s * (1.0f / 512.0f);
    const float var = sq * (1.0f / 512.0f) - mu * mu;
    const float rs  = rsqrtf(var + 1e-5f);
    const float4 wv = *(const float4*)&w[t * 4];
    const float4 bv = *(const float4*)&b[t * 4];
    bf16x4 o;
    o[0] = (__bf16)((v.x - mu) * rs * wv.x + bv.x);
    o[1] = (__bf16)((v.y - mu) * rs * wv.y + bv.y);
    o[2] = (__bf16)((v.z - mu) * rs * wv.z + bv.z);
    o[3] = (__bf16)((v.w - mu) * rs * wv.w + bv.w);
    *(bf16x4*)&out[(size_t)row * 512 + t * 4] = o;
}

// ---------------- bf16 GEMM, C = A[M,K] * Bt[N,K]^T, fused epilogues ----------------
// EPI 0: +bias -> bf16 | EPI 1: +bias, exact gelu -> bf16 | EPI 2: +bias +resid(f32) -> f32
template<int EPI>
__global__ __launch_bounds__(256)
void gemm_bt(const __bf16* __restrict__ A, const __bf16* __restrict__ Bt,
             const float* __restrict__ bias, const float* __restrict__ resid,
             __bf16* __restrict__ outb, float* __restrict__ outf,
             int M, int N, int K) {
    __shared__ __align__(16) __bf16 As[128 * 64];
    __shared__ __align__(16) __bf16 Bs[128 * 64];
    const int tid = threadIdx.x;
    const int w = tid >> 6, l = tid & 63;
    const int g = l >> 4, c = l & 15;
    const int m0 = blockIdx.y * 128, n0 = blockIdx.x * 128;
    const int wm = (w >> 1) * 64, wn = (w & 1) * 64;
    f32x4 acc[4][4] = {};

    for (int kt = 0; kt < K; kt += 64) {
        __syncthreads();
#pragma unroll
        for (int i = 0; i < 4; ++i) {
            const int cb = (i * 4 + w) * 64;          // wave-uniform chunk base
            const int chunk = cb + l;
            const int row = chunk >> 3, c8 = chunk & 7;
            GLOAD_LDS16(A  + (size_t)(m0 + row) * K + kt + c8 * 8, As + cb * 8);
            GLOAD_LDS16(Bt + (size_t)(n0 + row) * K + kt + c8 * 8, Bs + cb * 8);
        }
        __syncthreads();
#pragma unroll
        for (int kk = 0; kk < 2; ++kk) {
            bf16x8 av[4], bv[4];
#pragma unroll
            for (int mi = 0; mi < 4; ++mi)
                av[mi] = *(const bf16x8*)&As[(wm + mi * 16 + c) * 64 + kk * 32 + g * 8];
#pragma unroll
            for (int ni = 0; ni < 4; ++ni)
                bv[ni] = *(const bf16x8*)&Bs[(wn + ni * 16 + c) * 64 + kk * 32 + g * 8];
#pragma unroll
            for (int mi = 0; mi < 4; ++mi)
#pragma unroll
                for (int ni = 0; ni < 4; ++ni)
                    acc[mi][ni] = __builtin_amdgcn_mfma_f32_16x16x32_bf16(
                        av[mi], bv[ni], acc[mi][ni], 0, 0, 0);
        }
    }
#pragma unroll
    for (int mi = 0; mi < 4; ++mi)
#pragma unroll
        for (int ni = 0; ni < 4; ++ni)
#pragma unroll
            for (int r = 0; r < 4; ++r) {
                const int row = m0 + wm + mi * 16 + g * 4 + r;
                const int col = n0 + wn + ni * 16 + c;
                float v = acc[mi][ni][r] + bias[col];
                const size_t oidx = (size_t)row * N + col;
                if constexpr (EPI == 0) {
                    outb[oidx] = (__bf16)v;
                } else if constexpr (EPI == 1) {
                    outb[oidx] = (__bf16)(0.5f * v * (1.0f + erff(v * 0.70710678118654752f)));
                } else {
                    outf[oidx] = v + resid[oidx];
                }
            }
}

// ---------------- flash attention: swapped operands, 2 q-groups/wave, KV-split 2 ----------------
// Pipelined schedule (single-buffered, 33.8KB LDS):
//   B1 __syncthreads          -- K(kt),V(kt) prefetches landed; PV(kt-1) done
//   stage Vts <- vreg (scalar transpose ds_writes)
//   issue dist(kt) -> DPs     -- 4x global_load_lds, flies under QK^T
//   QK^T -> st[2][4]          -- reads Ks (landed at B1)
//   asm vmcnt(0) lgkm(0) + s_barrier  -- dist visible everywhere; QK^T reads done
//   issue K(kt+1)->Ks (gload_lds), V(kt+1)->vreg  -- fly across softmax+PV
//   softmax: dd from DPs + st -> exp2 -> cvt_pk bf16 -> permlane16/32_swap
//            redistribution: P NEVER touches LDS (T12). pa[t][kk] B-frags in regs.
//            (bit_cast assembly -- NO union: a union alloca went to scratch in
//             the previous rev and tripled FETCH_SIZE.)
//   PV (Vts, pa)
// P-word exchange derivation: lane(g',c) produces P[q=c][k=16ni+4g'+2p..+1] as
// word W[ni][p]; B-frag lane(g,c) needs words k={32kk+8g+2m,+1}. For (A,B)=
// (W[2kk][p],W[2kk+1][p]): permlane32_swap -> A'=[A0A1B0B1],B'=[A2A3B2B3];
// permlane16_swap -> A''=[A0A2B0B2]=T[kk][p], B''=[A1A3B1B3]=T[kk][p+2].
__global__ __launch_bounds__(256, 4)
void attn_kernel(const __bf16* __restrict__ qkv, const __bf16* __restrict__ distb,
                 const float* __restrict__ gamma, float* __restrict__ pacc,
                 float* __restrict__ pl) {
    __shared__ __align__(16) __bf16 Ks [64 * 64];    // K tile, linear + XOR swizzle
    __shared__ __align__(16) __bf16 Vts[64][72];     // V transposed, k XOR-swizzled
    __shared__ __align__(16) __bf16 DPs[128 * 64];   // dist, linear + XOR swizzle
    const int tid = threadIdx.x;
    const int w = tid >> 6, l = tid & 63;
    const int g = l >> 4, c = l & 15;
    const int qt = blockIdx.x, h = blockIdx.y;
    const int half = blockIdx.z & 1, b = blockIdx.z >> 1;
    const float gb = gamma[b];
    const size_t tok0 = (size_t)b * N_;
    const int qrow = 16 * w + c;                    // lane's local q row (group 0)
    const int wub = tid & 192;                      // w*64, wave-uniform lds chunk base
    const int srow = tid >> 3;                      // staging row (0..31)
    const int sd0  = (tid & 7) * 8;                 // staging d-offset

    // Q fragments for both groups, pre-scaled by SCALE*log2e
    bf16x8 qf[2][2];
#pragma unroll
    for (int t = 0; t < 2; ++t) {
        const size_t qbase = (tok0 + qt * 128 + 64 * t + qrow) * 1536 + h * 64;
#pragma unroll
        for (int kk = 0; kk < 2; ++kk) {
            const bf16x8 qv = *(const bf16x8*)&qkv[qbase + kk * 32 + g * 8];
#pragma unroll
            for (int j = 0; j < 8; ++j) qf[t][kk][j] = (__bf16)((float)qv[j] * SCALE_L2E_);
        }
    }

    f32x4 acc[2][4] = {};   // acc[t][di][r] = Onum[q=64t+qrow][d=16di+4g+r]
    float lsum[2] = {0.f, 0.f};
    bf16x8 vreg[2];

    auto issue_k = [&](int kt) {
#pragma unroll
        for (int i = 0; i < 2; ++i) {
            const int lin = i * 256 + tid;
            const int row = lin >> 3;
            const int col = ((tid & 7) ^ (row & 7)) * 8;   // source pre-swizzle
            GLOAD_LDS16(qkv + 512 + (tok0 + (size_t)kt * 64 + row) * 1536 + h * 64 + col,
                        Ks + (i * 256 + wub) * 8);
        }
    };
    auto issue_d = [&](int kt) {
#pragma unroll
        for (int i = 0; i < 4; ++i) {
            const int lin = i * 256 + tid;
            const int row = lin >> 3;
            const int col = ((tid & 7) ^ (row & 7)) * 8;   // source pre-swizzle
            GLOAD_LDS16(distb + (size_t)(qt * 128 + row) * N_ + kt * 64 + col,
                        DPs + (i * 256 + wub) * 8);
        }
    };
    auto issue_v = [&](int kt) {
#pragma unroll
        for (int rr = 0; rr < 2; ++rr) {
            const int r = srow + 32 * rr;
            vreg[rr] = *(const bf16x8*)
                &qkv[1024 + (tok0 + (size_t)kt * 64 + r) * 1536 + h * 64 + sd0];
        }
    };

    const int kt0 = half * (N_ / 128);              // 32 tiles per half
    const int ktend = kt0 + N_ / 128;
    issue_k(kt0);
    issue_v(kt0);

    for (int kt = kt0; kt < ktend; ++kt) {
        __syncthreads();     // B1: full drain -- K(kt)/V(kt) landed, PV(kt-1) done
        // stage V^T (scalar transpose) from prefetched regs
#pragma unroll
        for (int rr = 0; rr < 2; ++rr) {
            const int r = srow + 32 * rr;
            const int kp = r ^ sd0;    // sd0 = (sd0>>3)<<3 here
#pragma unroll
            for (int j = 0; j < 8; ++j) Vts[sd0 + j][kp] = vreg[rr][j];
        }
        issue_d(kt);         // dist flies under QK^T; only vm ops outstanding now
        __builtin_amdgcn_sched_barrier(0);

        // QK^T for all ni; st stays live across the barrier
        f32x4 st[2][4];
#pragma unroll
        for (int ni = 0; ni < 4; ++ni) {
            f32x4 s0 = {}, s1 = {};
#pragma unroll
            for (int kk = 0; kk < 2; ++kk) {
                const bf16x8 kf = *(const bf16x8*)
                    &Ks[((16 * ni + c) << 6) + ((kk * 32 + g * 8) ^ ((c & 7) << 3))];
                s0 = __builtin_amdgcn_mfma_f32_16x16x32_bf16(kf, qf[0][kk], s0, 0, 0, 0);
                s1 = __builtin_amdgcn_mfma_f32_16x16x32_bf16(kf, qf[1][kk], s1, 0, 0, 0);
            }
            st[0][ni] = s0; st[1][ni] = s1;
        }
        __builtin_amdgcn_sched_barrier(0);
        // B3: own dist gloads + Vts ds_writes drained, then block-wide barrier:
        // all waves' dist landed, all QK^T Ks-reads done, Vts visible.
        asm volatile("s_waitcnt vmcnt(0) lgkmcnt(0)\n\ts_barrier" ::: "memory");
        __builtin_amdgcn_sched_barrier(0);
        if (kt + 1 < ktend) {     // prefetch next tile; flies across softmax+PV
            issue_k(kt + 1);
            issue_v(kt + 1);
        }

        // softmax: dist from LDS + st regs -> P in registers (no LDS round-trip)
        bf16x8 pa[2][2];   // pa[t][kk]: PV B-frag, P[q=c][k=32kk+8g+j]
#pragma unroll
        for (int t = 0; t < 2; ++t) {
            uint32_t W[4][2];
#pragma unroll
            for (int ni = 0; ni < 4; ++ni) {
                const int row = 64 * t + qrow;
                const bf16x4 dd = *(const bf16x4*)
                    &DPs[(row << 6) + ((16 * ni + 4 * g) ^ ((c & 7) << 3))];
                float pv0, pv1, pv2, pv3;
                pv0 = __builtin_amdgcn_exp2f(fmaf(-gb, (float)dd[0], st[t][ni][0]));
                pv1 = __builtin_amdgcn_exp2f(fmaf(-gb, (float)dd[1], st[t][ni][1]));
                pv2 = __builtin_amdgcn_exp2f(fmaf(-gb, (float)dd[2], st[t][ni][2]));
                pv3 = __builtin_amdgcn_exp2f(fmaf(-gb, (float)dd[3], st[t][ni][3]));
                lsum[t] += (pv0 + pv1) + (pv2 + pv3);
                asm("v_cvt_pk_bf16_f32 %0, %1, %2" : "=v"(W[ni][0]) : "v"(pv0), "v"(pv1));
                asm("v_cvt_pk_bf16_f32 %0, %1, %2" : "=v"(W[ni][1]) : "v"(pv2), "v"(pv3));
            }
#pragma unroll
            for (int p = 0; p < 2; ++p)
#pragma unroll
                for (int q2 = 0; q2 < 2; ++q2) {
                    asm("v_permlane32_swap_b32 %0, %1"
                        : "+v"(W[2 * q2][p]), "+v"(W[2 * q2 + 1][p]));
                    asm("v_permlane16_swap_b32 %0, %1"
                        : "+v"(W[2 * q2][p]), "+v"(W[2 * q2 + 1][p]));
                }
#pragma unroll
            for (int kk = 0; kk < 2; ++kk) {
                const u32x4 words = {W[2 * kk][0], W[2 * kk][1],
                                     W[2 * kk + 1][0], W[2 * kk + 1][1]};
                pa[t][kk] = __builtin_bit_cast(bf16x8, words);
            }
        }

        // O^T += Vt * P^T for both groups, sharing each vb fragment
#pragma unroll
        for (int kk = 0; kk < 2; ++kk) {
#pragma unroll
            for (int di = 0; di < 4; ++di) {
                const int d = 16 * di + c;
                const int kp = (kk * 32 + g * 8) ^ ((d >> 3) << 3);
                const bf16x8 vb = *(const bf16x8*)&Vts[d][kp];
                acc[0][di] = __builtin_amdgcn_mfma_f32_16x16x32_bf16(vb, pa[0][kk], acc[0][di], 0, 0, 0);
                acc[1][di] = __builtin_amdgcn_mfma_f32_16x16x32_bf16(vb, pa[1][kk], acc[1][di], 0, 0, 0);
            }
        }
    }
    // partial l across the 4 g-lanes sharing each q row; write partials
#pragma unroll
    for (int t = 0; t < 2; ++t) {
        lsum[t] += __shfl_xor(lsum[t], 16);
        lsum[t] += __shfl_xor(lsum[t], 32);
        const int q = qt * 128 + 64 * t + qrow;
        if (g == 0)
            pl[(((size_t)half * B_ + b) * H_ + h) * N_ + q] = lsum[t];
#pragma unroll
        for (int di = 0; di < 4; ++di)
            *(f32x4*)&pacc[(((size_t)half * BN_) + b * N_ + q) * 512 + h * 64 + 16 * di + 4 * g]
                = acc[t][di];
    }
}

// ---------------- combine the two KV halves: (a0+a1)/(l0+l1) -> bf16 ----------------
__global__ __launch_bounds__(256)
void attn_finalize(const float* __restrict__ pacc, const float* __restrict__ pl,
                   __bf16* __restrict__ outp) {
    int idx = blockIdx.x * blockDim.x + threadIdx.x;      // one f32x4 (4 d) per thread
    const int stride = gridDim.x * blockDim.x;
    const int total = BN_ * 128;                          // 128 x4-groups per row
    for (; idx < total; idx += stride) {
        const int row = idx >> 7;                         // b*N + q
        const int d = (idx & 127) * 4;
        const int h = d >> 6;
        const int b = row >> 12, q = row & (N_ - 1);
        const float l0 = pl[(((size_t)0 * B_ + b) * H_ + h) * N_ + q];
        const float l1 = pl[(((size_t)1 * B_ + b) * H_ + h) * N_ + q];
        const float rl = 1.0f / (l0 + l1);
        const f32x4 a0 = *(const f32x4*)&pacc[((size_t)0 * BN_ + row) * 512 + d];
        const f32x4 a1 = *(const f32x4*)&pacc[((size_t)1 * BN_ + row) * 512 + d];
        bf16x4 o;
#pragma unroll
        for (int r = 0; r < 4; ++r) o[r] = (__bf16)((a0[r] + a1[r]) * rl);
        *(bf16x4*)&outp[(size_t)row * 512 + d] = o;
    }
}

// ---------------- launch ----------------
extern "C" void kernel_launch(void* const* d_in, const int* in_sizes, int n_in,
                              void* d_out, int out_size, void* d_ws, size_t ws_size,
                              hipStream_t stream) {
    (void)in_sizes; (void)n_in; (void)out_size; (void)ws_size;
    const float* x      = (const float*)d_in[0];
    const float* gamma  = (const float*)d_in[1];
    const float* dist   = (const float*)d_in[2];
    const float* ln1_w  = (const float*)d_in[3];
    const float* ln1_b  = (const float*)d_in[4];
    const float* qkv_w  = (const float*)d_in[5];
    const float* qkv_b  = (const float*)d_in[6];
    const float* proj_w = (const float*)d_in[7];
    const float* proj_b = (const float*)d_in[8];
    const float* ln2_w  = (const float*)d_in[9];
    const float* ln2_b  = (const float*)d_in[10];
    const float* fc1_w  = (const float*)d_in[11];
    const float* fc1_b  = (const float*)d_in[12];
    const float* fc2_w  = (const float*)d_in[13];
    const float* fc2_b  = (const float*)d_in[14];
    float* out = (float*)d_out;

    char* ws = (char*)d_ws;
    size_t off = 0;
    auto alloc = [&](size_t bytes) {
        void* p = ws + off; off = (off + bytes + 255) & ~(size_t)255; return p;
    };
    __bf16* distbf  = (__bf16*)alloc((size_t)N_ * N_ * 2);
    __bf16* qkv_wt  = (__bf16*)alloc((size_t)1536 * 512 * 2);
    __bf16* proj_wt = (__bf16*)alloc((size_t)512 * 512 * 2);
    __bf16* fc1_wt  = (__bf16*)alloc((size_t)2048 * 512 * 2);
    __bf16* fc2_wt  = (__bf16*)alloc((size_t)512 * 2048 * 2);
    __bf16* hbuf    = (__bf16*)alloc((size_t)BN_ * 512 * 2);
    __bf16* qkvbuf  = (__bf16*)alloc((size_t)BN_ * 1536 * 2);
    __bf16* attnbuf = (__bf16*)alloc((size_t)BN_ * 512 * 2);
    float*  x1buf   = (float*) alloc((size_t)BN_ * 512 * 4);
    __bf16* h2buf   = (__bf16*)alloc((size_t)BN_ * 512 * 2);
    __bf16* ffbuf   = (__bf16*)alloc((size_t)BN_ * 2048 * 2);
    float*  plbuf   = (float*) alloc((size_t)2 * B_ * H_ * N_ * 4);
    // O-numerator partials (2 x BN x 512 f32 = 33.6MB) alias ffbuf (33.6MB):
    // attn+finalize complete before the MLP phase touches ffbuf (stream order).
    float*  paccbuf = (float*)ffbuf;

    const dim3 tb(32, 8);
    transpose_to_bf16<<<dim3(1536/32,  512/32), tb, 0, stream>>>(qkv_w,  qkv_wt,  512, 1536);
    transpose_to_bf16<<<dim3( 512/32,  512/32), tb, 0, stream>>>(proj_w, proj_wt, 512,  512);
    transpose_to_bf16<<<dim3(2048/32,  512/32), tb, 0, stream>>>(fc1_w,  fc1_wt,  512, 2048);
    transpose_to_bf16<<<dim3( 512/32, 2048/32), tb, 0, stream>>>(fc2_w,  fc2_wt, 2048,  512);
    cvt_bf16<<<2048, 256, 0, stream>>>(dist, distbf, N_ * N_ / 4);

    ln_kernel<<<BN_, 128, 0, stream>>>(x, ln1_w, ln1_b, hbuf);
    gemm_bt<0><<<dim3(1536/128, BN_/128), 256, 0, stream>>>(
        hbuf, qkv_wt, qkv_b, nullptr, qkvbuf, nullptr, BN_, 1536, 512);
    attn_kernel<<<dim3(32, 8, 4), 256, 0, stream>>>(qkvbuf, distbf, gamma, paccbuf, plbuf);
    attn_finalize<<<2048, 256, 0, stream>>>(paccbuf, plbuf, attnbuf);
    gemm_bt<2><<<dim3(512/128, BN_/128), 256, 0, stream>>>(
        attnbuf, proj_wt, proj_b, x, nullptr, x1buf, BN_, 512, 512);
    ln_kernel<<<BN_, 128, 0, stream>>>(x1buf, ln2_w, ln2_b, h2buf);
    gemm_bt<1><<<dim3(2048/128, BN_/128), 256, 0, stream>>>(
        h2buf, fc1_wt, fc1_b, nullptr, ffbuf, nullptr, BN_, 2048, 512);
    gemm_bt<2><<<dim3(512/128, BN_/128), 256, 0, stream>>>(
        ffbuf, fc2_wt, fc2_b, x1buf, nullptr, out, BN_, 512, 2048);
}

// Round 5
// 306.423 us; speedup vs baseline: 1.3853x; 1.3853x over previous
//
#include <hip/hip_runtime.h>
#include <math.h>

typedef __bf16 bf16x8 __attribute__((ext_vector_type(8)));
typedef __bf16 bf16x4 __attribute__((ext_vector_type(4)));
typedef float  f32x4  __attribute__((ext_vector_type(4)));
typedef unsigned int u32x4 __attribute__((ext_vector_type(4)));

#define B_   2
#define N_   4096
#define D_   512
#define H_   8
#define FF_  2048
#define BN_  (B_*N_)
static constexpr float SCALE_ = 0.04419417382415922f;  // 512^-0.5
static constexpr float LOG2E_ = 1.44269504088896341f;
static constexpr float SCALE_L2E_ = SCALE_ * LOG2E_;   // fold log2e into Q scale

#define GLOAD_LDS16(g, l) __builtin_amdgcn_global_load_lds( \
    (const __attribute__((address_space(1))) void*)(g),     \
    (__attribute__((address_space(3))) void*)(l), 16, 0, 0)

// ---------------- weight transpose f32[R][C] -> bf16[C][R] ----------------
__global__ void transpose_to_bf16(const float* __restrict__ in, __bf16* __restrict__ out,
                                  int R, int C) {
    __shared__ float tile[32][33];
    const int c0 = blockIdx.x * 32, r0 = blockIdx.y * 32;
    const int tx = threadIdx.x, ty = threadIdx.y;   // (32,8)
#pragma unroll
    for (int i = 0; i < 4; ++i)
        tile[ty + 8*i][tx] = in[(size_t)(r0 + ty + 8*i) * C + c0 + tx];
    __syncthreads();
#pragma unroll
    for (int i = 0; i < 4; ++i)
        out[(size_t)(c0 + ty + 8*i) * R + r0 + tx] = (__bf16)tile[tx][ty + 8*i];
}

// ---------------- f32 -> bf16 elementwise (dist), folds log2e ----------------
__global__ void cvt_bf16(const float* __restrict__ in, __bf16* __restrict__ out, int n4) {
    int i = blockIdx.x * blockDim.x + threadIdx.x;
    const int stride = gridDim.x * blockDim.x;
    for (; i < n4; i += stride) {
        float4 v = ((const float4*)in)[i];
        bf16x4 o;
        o[0] = (__bf16)(v.x * LOG2E_); o[1] = (__bf16)(v.y * LOG2E_);
        o[2] = (__bf16)(v.z * LOG2E_); o[3] = (__bf16)(v.w * LOG2E_);
        ((bf16x4*)out)[i] = o;
    }
}

// ---------------- LayerNorm f32 -> bf16, one row (512) per block of 128 ----------------
__global__ __launch_bounds__(128)
void ln_kernel(const float* __restrict__ x, const float* __restrict__ w,
               const float* __restrict__ b, __bf16* __restrict__ out) {
    const int row = blockIdx.x, t = threadIdx.x;
    const float4 v = *(const float4*)&x[(size_t)row * 512 + t * 4];
    float s  = v.x + v.y + v.z + v.w;
    float sq = v.x*v.x + v.y*v.y + v.z*v.z + v.w*v.w;
#pragma unroll
    for (int mk = 1; mk < 64; mk <<= 1) { s += __shfl_xor(s, mk); sq += __shfl_xor(sq, mk); }
    __shared__ float ps[2][2];
    if ((t & 63) == 0) { ps[t >> 6][0] = s; ps[t >> 6][1] = sq; }
    __syncthreads();
    s = ps[0][0] + ps[1][0]; sq = ps[0][1] + ps[1][1];
    const float mu  = s * (1.0f / 512.0f);
    const float var = sq * (1.0f / 512.0f) - mu * mu;
    const float rs  = rsqrtf(var + 1e-5f);
    const float4 wv = *(const float4*)&w[t * 4];
    const float4 bv = *(const float4*)&b[t * 4];
    bf16x4 o;
    o[0] = (__bf16)((v.x - mu) * rs * wv.x + bv.x);
    o[1] = (__bf16)((v.y - mu) * rs * wv.y + bv.y);
    o[2] = (__bf16)((v.z - mu) * rs * wv.z + bv.z);
    o[3] = (__bf16)((v.w - mu) * rs * wv.w + bv.w);
    *(bf16x4*)&out[(size_t)row * 512 + t * 4] = o;
}

// ---------------- bf16 GEMM, C = A[M,K] * Bt[N,K]^T, fused epilogues ----------------
// EPI 0: +bias -> bf16 | EPI 1: +bias, exact gelu -> bf16 | EPI 2: +bias +resid(f32) -> f32
template<int EPI>
__global__ __launch_bounds__(256)
void gemm_bt(const __bf16* __restrict__ A, const __bf16* __restrict__ Bt,
             const float* __restrict__ bias, const float* __restrict__ resid,
             __bf16* __restrict__ outb, float* __restrict__ outf,
             int M, int N, int K) {
    __shared__ __align__(16) __bf16 As[128 * 64];
    __shared__ __align__(16) __bf16 Bs[128 * 64];
    const int tid = threadIdx.x;
    const int w = tid >> 6, l = tid & 63;
    const int g = l >> 4, c = l & 15;
    const int m0 = blockIdx.y * 128, n0 = blockIdx.x * 128;
    const int wm = (w >> 1) * 64, wn = (w & 1) * 64;
    f32x4 acc[4][4] = {};

    for (int kt = 0; kt < K; kt += 64) {
        __syncthreads();
#pragma unroll
        for (int i = 0; i < 4; ++i) {
            const int cb = (i * 4 + w) * 64;          // wave-uniform chunk base
            const int chunk = cb + l;
            const int row = chunk >> 3, c8 = chunk & 7;
            GLOAD_LDS16(A  + (size_t)(m0 + row) * K + kt + c8 * 8, As + cb * 8);
            GLOAD_LDS16(Bt + (size_t)(n0 + row) * K + kt + c8 * 8, Bs + cb * 8);
        }
        __syncthreads();
#pragma unroll
        for (int kk = 0; kk < 2; ++kk) {
            bf16x8 av[4], bv[4];
#pragma unroll
            for (int mi = 0; mi < 4; ++mi)
                av[mi] = *(const bf16x8*)&As[(wm + mi * 16 + c) * 64 + kk * 32 + g * 8];
#pragma unroll
            for (int ni = 0; ni < 4; ++ni)
                bv[ni] = *(const bf16x8*)&Bs[(wn + ni * 16 + c) * 64 + kk * 32 + g * 8];
#pragma unroll
            for (int mi = 0; mi < 4; ++mi)
#pragma unroll
                for (int ni = 0; ni < 4; ++ni)
                    acc[mi][ni] = __builtin_amdgcn_mfma_f32_16x16x32_bf16(
                        av[mi], bv[ni], acc[mi][ni], 0, 0, 0);
        }
    }
#pragma unroll
    for (int mi = 0; mi < 4; ++mi)
#pragma unroll
        for (int ni = 0; ni < 4; ++ni)
#pragma unroll
            for (int r = 0; r < 4; ++r) {
                const int row = m0 + wm + mi * 16 + g * 4 + r;
                const int col = n0 + wn + ni * 16 + c;
                float v = acc[mi][ni][r] + bias[col];
                const size_t oidx = (size_t)row * N + col;
                if constexpr (EPI == 0) {
                    outb[oidx] = (__bf16)v;
                } else if constexpr (EPI == 1) {
                    outb[oidx] = (__bf16)(0.5f * v * (1.0f + erff(v * 0.70710678118654752f)));
                } else {
                    outf[oidx] = v + resid[oidx];
                }
            }
}

// ---------------- flash attention: swapped operands, 2 q-groups/wave ----------------
// NO KV-split: 512 blocks (= exactly 2/CU), each owns all 4096 keys for its
// 128 q-rows. __launch_bounds__(256,2) -> 256-reg budget, live set ~140 regs,
// NO SPILLS (r3/r4's 230MB spill-FETCH came from the 128-reg cap at occupancy 4).
// Finalize fused: O = acc * (1/lsum) -> bf16, written directly (pacc/pl gone).
// Pipelined schedule (single-buffered, 33.8KB LDS):
//   B1 __syncthreads          -- K(kt),V(kt) prefetches landed; PV(kt-1) done
//   stage Vts <- vreg (scalar transpose ds_writes)
//   issue dist(kt) -> DPs     -- 4x global_load_lds, flies under QK^T
//   QK^T -> st[2][4]          -- reads Ks (landed at B1)
//   asm vmcnt(0) lgkm(0) + s_barrier  -- dist visible; QK^T Ks-reads done
//   issue K(kt+1)->Ks (gload_lds), V(kt+1)->vreg  -- fly across softmax+PV
//   softmax: dd from DPs + st -> exp2 -> cvt_pk bf16 -> permlane16/32_swap
//            P never touches LDS; pa[t][kk] B-frags assembled in regs.
//   PV (Vts, pa)
__global__ __launch_bounds__(256, 2)
void attn_kernel(const __bf16* __restrict__ qkv, const __bf16* __restrict__ distb,
                 const float* __restrict__ gamma, __bf16* __restrict__ outp) {
    __shared__ __align__(16) __bf16 Ks [64 * 64];    // K tile, linear + XOR swizzle
    __shared__ __align__(16) __bf16 Vts[64][72];     // V transposed, k XOR-swizzled
    __shared__ __align__(16) __bf16 DPs[128 * 64];   // dist, linear + XOR swizzle
    const int tid = threadIdx.x;
    const int w = tid >> 6, l = tid & 63;
    const int g = l >> 4, c = l & 15;
    const int qt = blockIdx.x, h = blockIdx.y;
    const int b = blockIdx.z;
    const float gb = gamma[b];
    const size_t tok0 = (size_t)b * N_;
    const int qrow = 16 * w + c;                    // lane's local q row (group 0)
    const int wub = tid & 192;                      // w*64, wave-uniform lds chunk base
    const int srow = tid >> 3;                      // staging row (0..31)
    const int sd0  = (tid & 7) * 8;                 // staging d-offset

    // Q fragments for both groups, pre-scaled by SCALE*log2e
    bf16x8 qf[2][2];
#pragma unroll
    for (int t = 0; t < 2; ++t) {
        const size_t qbase = (tok0 + qt * 128 + 64 * t + qrow) * 1536 + h * 64;
#pragma unroll
        for (int kk = 0; kk < 2; ++kk) {
            const bf16x8 qv = *(const bf16x8*)&qkv[qbase + kk * 32 + g * 8];
#pragma unroll
            for (int j = 0; j < 8; ++j) qf[t][kk][j] = (__bf16)((float)qv[j] * SCALE_L2E_);
        }
    }

    f32x4 acc[2][4] = {};   // acc[t][di][r] = Onum[q=64t+qrow][d=16di+4g+r]
    float lsum[2] = {0.f, 0.f};
    bf16x8 vreg[2];

    auto issue_k = [&](int kt) {
#pragma unroll
        for (int i = 0; i < 2; ++i) {
            const int lin = i * 256 + tid;
            const int row = lin >> 3;
            const int col = ((tid & 7) ^ (row & 7)) * 8;   // source pre-swizzle
            GLOAD_LDS16(qkv + 512 + (tok0 + (size_t)kt * 64 + row) * 1536 + h * 64 + col,
                        Ks + (i * 256 + wub) * 8);
        }
    };
    auto issue_d = [&](int kt) {
#pragma unroll
        for (int i = 0; i < 4; ++i) {
            const int lin = i * 256 + tid;
            const int row = lin >> 3;
            const int col = ((tid & 7) ^ (row & 7)) * 8;   // source pre-swizzle
            GLOAD_LDS16(distb + (size_t)(qt * 128 + row) * N_ + kt * 64 + col,
                        DPs + (i * 256 + wub) * 8);
        }
    };
    auto issue_v = [&](int kt) {
#pragma unroll
        for (int rr = 0; rr < 2; ++rr) {
            const int r = srow + 32 * rr;
            vreg[rr] = *(const bf16x8*)
                &qkv[1024 + (tok0 + (size_t)kt * 64 + r) * 1536 + h * 64 + sd0];
        }
    };

    const int ktend = N_ / 64;                      // 64 tiles, all keys
    issue_k(0);
    issue_v(0);

    for (int kt = 0; kt < ktend; ++kt) {
        __syncthreads();     // B1: full drain -- K(kt)/V(kt) landed, PV(kt-1) done
        // stage V^T (scalar transpose) from prefetched regs
#pragma unroll
        for (int rr = 0; rr < 2; ++rr) {
            const int r = srow + 32 * rr;
            const int kp = r ^ sd0;    // sd0 = (sd0>>3)<<3 here
#pragma unroll
            for (int j = 0; j < 8; ++j) Vts[sd0 + j][kp] = vreg[rr][j];
        }
        issue_d(kt);         // dist flies under QK^T; only vm ops outstanding now
        __builtin_amdgcn_sched_barrier(0);

        // QK^T for all ni; st stays live across the barrier
        f32x4 st[2][4];
#pragma unroll
        for (int ni = 0; ni < 4; ++ni) {
            f32x4 s0 = {}, s1 = {};
#pragma unroll
            for (int kk = 0; kk < 2; ++kk) {
                const bf16x8 kf = *(const bf16x8*)
                    &Ks[((16 * ni + c) << 6) + ((kk * 32 + g * 8) ^ ((c & 7) << 3))];
                s0 = __builtin_amdgcn_mfma_f32_16x16x32_bf16(kf, qf[0][kk], s0, 0, 0, 0);
                s1 = __builtin_amdgcn_mfma_f32_16x16x32_bf16(kf, qf[1][kk], s1, 0, 0, 0);
            }
            st[0][ni] = s0; st[1][ni] = s1;
        }
        __builtin_amdgcn_sched_barrier(0);
        // B3: own dist gloads + Vts ds_writes drained, then block-wide barrier:
        // all waves' dist landed, all QK^T Ks-reads done, Vts visible.
        asm volatile("s_waitcnt vmcnt(0) lgkmcnt(0)\n\ts_barrier" ::: "memory");
        __builtin_amdgcn_sched_barrier(0);
        if (kt + 1 < ktend) {     // prefetch next tile; flies across softmax+PV
            issue_k(kt + 1);
            issue_v(kt + 1);
        }

        // softmax: dist from LDS + st regs -> P in registers (no LDS round-trip)
        bf16x8 pa[2][2];   // pa[t][kk]: PV B-frag, P[q=c][k=32kk+8g+j]
#pragma unroll
        for (int t = 0; t < 2; ++t) {
            uint32_t W[4][2];
#pragma unroll
            for (int ni = 0; ni < 4; ++ni) {
                const int row = 64 * t + qrow;
                const bf16x4 dd = *(const bf16x4*)
                    &DPs[(row << 6) + ((16 * ni + 4 * g) ^ ((c & 7) << 3))];
                float pv0, pv1, pv2, pv3;
                pv0 = __builtin_amdgcn_exp2f(fmaf(-gb, (float)dd[0], st[t][ni][0]));
                pv1 = __builtin_amdgcn_exp2f(fmaf(-gb, (float)dd[1], st[t][ni][1]));
                pv2 = __builtin_amdgcn_exp2f(fmaf(-gb, (float)dd[2], st[t][ni][2]));
                pv3 = __builtin_amdgcn_exp2f(fmaf(-gb, (float)dd[3], st[t][ni][3]));
                lsum[t] += (pv0 + pv1) + (pv2 + pv3);
                asm("v_cvt_pk_bf16_f32 %0, %1, %2" : "=v"(W[ni][0]) : "v"(pv0), "v"(pv1));
                asm("v_cvt_pk_bf16_f32 %0, %1, %2" : "=v"(W[ni][1]) : "v"(pv2), "v"(pv3));
            }
#pragma unroll
            for (int p = 0; p < 2; ++p)
#pragma unroll
                for (int q2 = 0; q2 < 2; ++q2) {
                    asm("v_permlane32_swap_b32 %0, %1"
                        : "+v"(W[2 * q2][p]), "+v"(W[2 * q2 + 1][p]));
                    asm("v_permlane16_swap_b32 %0, %1"
                        : "+v"(W[2 * q2][p]), "+v"(W[2 * q2 + 1][p]));
                }
#pragma unroll
            for (int kk = 0; kk < 2; ++kk) {
                const u32x4 words = {W[2 * kk][0], W[2 * kk][1],
                                     W[2 * kk + 1][0], W[2 * kk + 1][1]};
                pa[t][kk] = __builtin_bit_cast(bf16x8, words);
            }
        }

        // O^T += Vt * P^T for both groups, sharing each vb fragment
#pragma unroll
        for (int kk = 0; kk < 2; ++kk) {
#pragma unroll
            for (int di = 0; di < 4; ++di) {
                const int d = 16 * di + c;
                const int kp = (kk * 32 + g * 8) ^ ((d >> 3) << 3);
                const bf16x8 vb = *(const bf16x8*)&Vts[d][kp];
                acc[0][di] = __builtin_amdgcn_mfma_f32_16x16x32_bf16(vb, pa[0][kk], acc[0][di], 0, 0, 0);
                acc[1][di] = __builtin_amdgcn_mfma_f32_16x16x32_bf16(vb, pa[1][kk], acc[1][di], 0, 0, 0);
            }
        }
    }
    // fused finalize: l across the 4 g-lanes sharing each q row; O = acc/l -> bf16
#pragma unroll
    for (int t = 0; t < 2; ++t) {
        lsum[t] += __shfl_xor(lsum[t], 16);
        lsum[t] += __shfl_xor(lsum[t], 32);
        const float rl = 1.0f / lsum[t];
        const int q = qt * 128 + 64 * t + qrow;
#pragma unroll
        for (int di = 0; di < 4; ++di) {
            bf16x4 o;
#pragma unroll
            for (int r = 0; r < 4; ++r) o[r] = (__bf16)(acc[t][di][r] * rl);
            *(bf16x4*)&outp[((size_t)(b * N_ + q)) * 512 + h * 64 + 16 * di + 4 * g] = o;
        }
    }
}

// ---------------- launch ----------------
extern "C" void kernel_launch(void* const* d_in, const int* in_sizes, int n_in,
                              void* d_out, int out_size, void* d_ws, size_t ws_size,
                              hipStream_t stream) {
    (void)in_sizes; (void)n_in; (void)out_size; (void)ws_size;
    const float* x      = (const float*)d_in[0];
    const float* gamma  = (const float*)d_in[1];
    const float* dist   = (const float*)d_in[2];
    const float* ln1_w  = (const float*)d_in[3];
    const float* ln1_b  = (const float*)d_in[4];
    const float* qkv_w  = (const float*)d_in[5];
    const float* qkv_b  = (const float*)d_in[6];
    const float* proj_w = (const float*)d_in[7];
    const float* proj_b = (const float*)d_in[8];
    const float* ln2_w  = (const float*)d_in[9];
    const float* ln2_b  = (const float*)d_in[10];
    const float* fc1_w  = (const float*)d_in[11];
    const float* fc1_b  = (const float*)d_in[12];
    const float* fc2_w  = (const float*)d_in[13];
    const float* fc2_b  = (const float*)d_in[14];
    float* out = (float*)d_out;

    char* ws = (char*)d_ws;
    size_t off = 0;
    auto alloc = [&](size_t bytes) {
        void* p = ws + off; off = (off + bytes + 255) & ~(size_t)255; return p;
    };
    __bf16* distbf  = (__bf16*)alloc((size_t)N_ * N_ * 2);
    __bf16* qkv_wt  = (__bf16*)alloc((size_t)1536 * 512 * 2);
    __bf16* proj_wt = (__bf16*)alloc((size_t)512 * 512 * 2);
    __bf16* fc1_wt  = (__bf16*)alloc((size_t)2048 * 512 * 2);
    __bf16* fc2_wt  = (__bf16*)alloc((size_t)512 * 2048 * 2);
    __bf16* hbuf    = (__bf16*)alloc((size_t)BN_ * 512 * 2);
    __bf16* qkvbuf  = (__bf16*)alloc((size_t)BN_ * 1536 * 2);
    __bf16* attnbuf = (__bf16*)alloc((size_t)BN_ * 512 * 2);
    float*  x1buf   = (float*) alloc((size_t)BN_ * 512 * 4);
    __bf16* h2buf   = (__bf16*)alloc((size_t)BN_ * 512 * 2);
    __bf16* ffbuf   = (__bf16*)alloc((size_t)BN_ * 2048 * 2);

    const dim3 tb(32, 8);
    transpose_to_bf16<<<dim3(1536/32,  512/32), tb, 0, stream>>>(qkv_w,  qkv_wt,  512, 1536);
    transpose_to_bf16<<<dim3( 512/32,  512/32), tb, 0, stream>>>(proj_w, proj_wt, 512,  512);
    transpose_to_bf16<<<dim3(2048/32,  512/32), tb, 0, stream>>>(fc1_w,  fc1_wt,  512, 2048);
    transpose_to_bf16<<<dim3( 512/32, 2048/32), tb, 0, stream>>>(fc2_w,  fc2_wt, 2048,  512);
    cvt_bf16<<<2048, 256, 0, stream>>>(dist, distbf, N_ * N_ / 4);

    ln_kernel<<<BN_, 128, 0, stream>>>(x, ln1_w, ln1_b, hbuf);
    gemm_bt<0><<<dim3(1536/128, BN_/128), 256, 0, stream>>>(
        hbuf, qkv_wt, qkv_b, nullptr, qkvbuf, nullptr, BN_, 1536, 512);
    attn_kernel<<<dim3(32, 8, 2), 256, 0, stream>>>(qkvbuf, distbf, gamma, attnbuf);
    gemm_bt<2><<<dim3(512/128, BN_/128), 256, 0, stream>>>(
        attnbuf, proj_wt, proj_b, x, nullptr, x1buf, BN_, 512, 512);
    ln_kernel<<<BN_, 128, 0, stream>>>(x1buf, ln2_w, ln2_b, h2buf);
    gemm_bt<1><<<dim3(2048/128, BN_/128), 256, 0, stream>>>(
        h2buf, fc1_wt, fc1_b, nullptr, ffbuf, nullptr, BN_, 2048, 512);
    gemm_bt<2><<<dim3(512/128, BN_/128), 256, 0, stream>>>(
        ffbuf, fc2_wt, fc2_b, x1buf, nullptr, out, BN_, 512, 2048);
}